// Round 1
// baseline (213.796 us; speedup 1.0000x reference)
//
#include <hip/hip_runtime.h>
#include <hip/hip_bf16.h>

// BlockAttention: paged KV-cache prefill attention with block-causal
// (diffusion) mask. B=4, LQ=512, HQ=16, HKV=8, D=128, CTX=2048, LK=2560.
// Mask is uniform per 64-row q-tile => no masking, just loop bound.

#define B_    4
#define LQ_   512
#define HQ_   16
#define HKV_  8
#define D_    128
#define BLKSZ_ 256
#define BPS_  8
#define CTX_  2048
#define DIFFB_ 128
#define KT_   64
#define SCALE_ 0.08838834764831845f

typedef __attribute__((ext_vector_type(4))) float f32x4;
typedef __attribute__((ext_vector_type(8))) short bf16x8;

__device__ __forceinline__ unsigned short f2bf(float f) {
  union { float f; unsigned u; } x; x.f = f;
  unsigned r = x.u + 0x7FFFu + ((x.u >> 16) & 1u);   // RNE
  return (unsigned short)(r >> 16);
}

__global__ __launch_bounds__(512)
void block_attn_kernel(const float* __restrict__ qg,
                       const float* __restrict__ kcur,
                       const float* __restrict__ vcur,
                       const float* __restrict__ kcache,
                       const float* __restrict__ vcache,
                       const int*   __restrict__ btab,
                       float*       __restrict__ out) {
  // grid: 256 blocks = B(4) * HKV(8) * qtiles(8); block = 512 threads = 8 waves
  const int blk  = blockIdx.x;
  const int qb   = blk & 7;          // 64-row q tile index
  const int hkv  = (blk >> 3) & 7;
  const int b    = blk >> 6;
  const int tid  = threadIdx.x;
  const int wave = tid >> 6;
  const int lane = tid & 63;
  const int lo   = lane & 15;        // MFMA col / row-within-16
  const int hi   = lane >> 4;        // MFMA k-group
  const int hq   = hkv * 2 + (wave >> 2);        // GQA: hq//2 == hkv
  const int qrow0 = qb * 64 + (wave & 3) * 16;   // this wave's 16 q rows
  // diffusion-block causal limit — uniform across the 64-row tile
  const int limit  = CTX_ + (qb / 2 + 1) * DIFFB_;
  const int ntiles = limit / KT_;

  __shared__ short Kl[KT_][D_ + 8];        // K tile, row-major (+pad)
  __shared__ short Vl[D_][KT_ + 8];        // V tile TRANSPOSED (+pad)
  __shared__ short Pl[8][16][KT_ + 8];     // per-wave P round-trip

  // ---- Q fragments (scaled, bf16). a_frag: A[row=lo][k=hi*8+j] ----
  bf16x8 qf[4];
  {
    const float* qr = qg + ((size_t)((b * LQ_ + qrow0 + lo)) * HQ_ + hq) * D_;
#pragma unroll
    for (int db = 0; db < 4; ++db) {
      const int d0 = db * 32 + hi * 8;
      f32x4 a = *(const f32x4*)(qr + d0);
      f32x4 c = *(const f32x4*)(qr + d0 + 4);
      bf16x8 f;
      f[0] = (short)f2bf(a[0] * SCALE_); f[1] = (short)f2bf(a[1] * SCALE_);
      f[2] = (short)f2bf(a[2] * SCALE_); f[3] = (short)f2bf(a[3] * SCALE_);
      f[4] = (short)f2bf(c[0] * SCALE_); f[5] = (short)f2bf(c[1] * SCALE_);
      f[6] = (short)f2bf(c[2] * SCALE_); f[7] = (short)f2bf(c[3] * SCALE_);
      qf[db] = f;
    }
  }

  f32x4 oacc[8];
#pragma unroll
  for (int i = 0; i < 8; ++i) oacc[i] = (f32x4){0.f, 0.f, 0.f, 0.f};
  float mrow[4], lrow[4];
#pragma unroll
  for (int i = 0; i < 4; ++i) { mrow[i] = -1e30f; lrow[i] = 0.f; }

  for (int t = 0; t < ntiles; ++t) {
    __syncthreads();   // previous iteration's LDS reads done
    // ---- stage K (row-major) and V (transposed) fp32 -> bf16 ----
    {
      const int c = tid >> 3;          // kv column within tile (0..63)
      const int e = tid & 7;
      const int kgi = t * KT_ + c;     // global key index
      const float *kr, *vr;
      if (kgi < CTX_) {
        const int pb = btab[b * BPS_ + (kgi >> 8)];
        const size_t base = ((size_t)(pb * BLKSZ_ + (kgi & 255)) * HKV_ + hkv) * D_;
        kr = kcache + base; vr = vcache + base;
      } else {
        const size_t base = ((size_t)(b * LQ_ + (kgi - CTX_)) * HKV_ + hkv) * D_;
        kr = kcur + base;  vr = vcur + base;
      }
#pragma unroll
      for (int i2 = 0; i2 < 4; ++i2) {
        const int d0 = (e + i2 * 8) * 4;
        f32x4 kv = *(const f32x4*)(kr + d0);
        unsigned w0 = (unsigned)f2bf(kv[0]) | ((unsigned)f2bf(kv[1]) << 16);
        unsigned w1 = (unsigned)f2bf(kv[2]) | ((unsigned)f2bf(kv[3]) << 16);
        *(unsigned*)&Kl[c][d0]     = w0;
        *(unsigned*)&Kl[c][d0 + 2] = w1;
        f32x4 vv = *(const f32x4*)(vr + d0);
        Vl[d0 + 0][c] = (short)f2bf(vv[0]);
        Vl[d0 + 1][c] = (short)f2bf(vv[1]);
        Vl[d0 + 2][c] = (short)f2bf(vv[2]);
        Vl[d0 + 3][c] = (short)f2bf(vv[3]);
      }
    }
    __syncthreads();

    // ---- S = Q K^T  (16 q rows x 64 cols), 16 MFMAs ----
    f32x4 sacc[4];
#pragma unroll
    for (int cs = 0; cs < 4; ++cs) sacc[cs] = (f32x4){0.f, 0.f, 0.f, 0.f};
#pragma unroll
    for (int cs = 0; cs < 4; ++cs) {
#pragma unroll
      for (int db = 0; db < 4; ++db) {
        // b_frag: B[k=hi*8+j][col=lo] = K[cs*16+lo][db*32+hi*8+j]
        bf16x8 kf = *(const bf16x8*)&Kl[cs * 16 + lo][db * 32 + hi * 8];
        sacc[cs] = __builtin_amdgcn_mfma_f32_16x16x32_bf16(qf[db], kf, sacc[cs], 0, 0, 0);
      }
    }

    // ---- online softmax (row = hi*4+i, cols spread over lanes 0..15) ----
#pragma unroll
    for (int i = 0; i < 4; ++i) {
      float mx = fmaxf(fmaxf(sacc[0][i], sacc[1][i]), fmaxf(sacc[2][i], sacc[3][i]));
      mx = fmaxf(mx, __shfl_xor(mx, 1));
      mx = fmaxf(mx, __shfl_xor(mx, 2));
      mx = fmaxf(mx, __shfl_xor(mx, 4));
      mx = fmaxf(mx, __shfl_xor(mx, 8));
      const float mnew = fmaxf(mrow[i], mx);
      const float sc = __expf(mrow[i] - mnew);
      mrow[i] = mnew;
      float rs = 0.f;
#pragma unroll
      for (int cs = 0; cs < 4; ++cs) {
        const float p = __expf(sacc[cs][i] - mnew);
        sacc[cs][i] = p;
        rs += p;
      }
      rs += __shfl_xor(rs, 1);
      rs += __shfl_xor(rs, 2);
      rs += __shfl_xor(rs, 4);
      rs += __shfl_xor(rs, 8);
      lrow[i] = lrow[i] * sc + rs;
#pragma unroll
      for (int dt = 0; dt < 8; ++dt) oacc[dt][i] *= sc;
    }

    // ---- P -> LDS (wave-private; DS ops are in-order within a wave) ----
#pragma unroll
    for (int cs = 0; cs < 4; ++cs)
#pragma unroll
      for (int i = 0; i < 4; ++i)
        Pl[wave][hi * 4 + i][cs * 16 + lo] = (short)f2bf(sacc[cs][i]);

    // ---- O += P V  (16 MFMAs) ----
#pragma unroll
    for (int ch = 0; ch < 2; ++ch) {
      // a_frag: P[row=lo][k=ch*32+hi*8+j]
      bf16x8 pf = *(const bf16x8*)&Pl[wave][lo][ch * 32 + hi * 8];
#pragma unroll
      for (int dt = 0; dt < 8; ++dt) {
        // b_frag: V[k=ch*32+hi*8+j][col=dt*16+lo] = Vl[dt*16+lo][ch*32+hi*8+j]
        bf16x8 vf = *(const bf16x8*)&Vl[dt * 16 + lo][ch * 32 + hi * 8];
        oacc[dt] = __builtin_amdgcn_mfma_f32_16x16x32_bf16(pf, vf, oacc[dt], 0, 0, 0);
      }
    }
  }

  // ---- epilogue: out[b][q][hq][d] = oacc / l ----
#pragma unroll
  for (int i = 0; i < 4; ++i) {
    const int row = hi * 4 + i;
    const float inv = 1.f / lrow[i];
    float* orow = out + ((size_t)(b * LQ_ + qrow0 + row) * HQ_ + hq) * D_;
#pragma unroll
    for (int dt = 0; dt < 8; ++dt)
      orow[dt * 16 + lo] = oacc[dt][i] * inv;
  }
}

extern "C" void kernel_launch(void* const* d_in, const int* in_sizes, int n_in,
                              void* d_out, int out_size, void* d_ws, size_t ws_size,
                              hipStream_t stream) {
  (void)in_sizes; (void)n_in; (void)out_size; (void)d_ws; (void)ws_size;
  const float* q      = (const float*)d_in[0];
  const float* k      = (const float*)d_in[1];
  const float* v      = (const float*)d_in[2];
  const float* kcache = (const float*)d_in[3];
  const float* vcache = (const float*)d_in[4];
  const int*   btab   = (const int*)d_in[5];
  // d_in[6] (allow_mask) is implied by the loop bound — not read.
  float* out = (float*)d_out;

  block_attn_kernel<<<dim3(B_ * HKV_ * (LQ_ / 64)), dim3(512), 0, stream>>>(
      q, k, v, kcache, vcache, btab, out);
}

// Round 2
// 130.144 us; speedup vs baseline: 1.6428x; 1.6428x over previous
//
#include <hip/hip_runtime.h>
#include <hip/hip_bf16.h>

// BlockAttention: paged KV-cache prefill attention with block-causal
// (diffusion) mask. B=4, LQ=512, HQ=16, HKV=8, D=128, CTX=2048, LK=2560.
// Mask is uniform per 64-row q-tile => no masking, just loop bound.
//
// R1: (a) XCD-aware block index (qb in HIGH bits so the 8 q-tile blocks
//     sharing one (b,hkv) K/V panel land on the SAME XCD's L2),
//     (b) register-prefetch pipeline: issue tile t+1's global loads right
//     after the post-stage barrier so HBM latency hides under compute(t).

#define B_    4
#define LQ_   512
#define HQ_   16
#define HKV_  8
#define D_    128
#define BLKSZ_ 256
#define BPS_  8
#define CTX_  2048
#define DIFFB_ 128
#define KT_   64
#define SCALE_ 0.08838834764831845f

typedef __attribute__((ext_vector_type(4))) float f32x4;
typedef __attribute__((ext_vector_type(8))) short bf16x8;

__device__ __forceinline__ unsigned short f2bf(float f) {
  union { float f; unsigned u; } x; x.f = f;
  unsigned r = x.u + 0x7FFFu + ((x.u >> 16) & 1u);   // RNE
  return (unsigned short)(r >> 16);
}

__global__ __launch_bounds__(512)
void block_attn_kernel(const float* __restrict__ qg,
                       const float* __restrict__ kcur,
                       const float* __restrict__ vcur,
                       const float* __restrict__ kcache,
                       const float* __restrict__ vcache,
                       const int*   __restrict__ btab,
                       float*       __restrict__ out) {
  // grid: 256 blocks; index = qb*32 + b*8 + hkv  (qb in high bits -> same
  // (b,hkv) shares an XCD under round-robin dispatch). 512 thr = 8 waves.
  const int blk  = blockIdx.x;
  const int hkv  = blk & 7;
  const int b    = (blk >> 3) & 3;
  const int qb   = blk >> 5;         // 64-row q tile index
  const int tid  = threadIdx.x;
  const int wave = tid >> 6;
  const int lane = tid & 63;
  const int lo   = lane & 15;        // MFMA col / row-within-16
  const int hi   = lane >> 4;        // MFMA k-group
  const int hq   = hkv * 2 + (wave >> 2);        // GQA: hq//2 == hkv
  const int qrow0 = qb * 64 + (wave & 3) * 16;   // this wave's 16 q rows
  // diffusion-block causal limit — uniform across the 64-row tile
  const int limit  = CTX_ + (qb / 2 + 1) * DIFFB_;
  const int ntiles = limit / KT_;

  __shared__ short Kl[KT_][D_ + 8];        // K tile, row-major (+pad)
  __shared__ short Vl[D_][KT_ + 8];        // V tile TRANSPOSED (+pad)
  __shared__ short Pl[8][16][KT_ + 8];     // per-wave P round-trip

  // ---- Q fragments (scaled, bf16). a_frag: A[row=lo][k=hi*8+j] ----
  bf16x8 qf[4];
  {
    const float* qr = qg + ((size_t)((b * LQ_ + qrow0 + lo)) * HQ_ + hq) * D_;
#pragma unroll
    for (int db = 0; db < 4; ++db) {
      const int d0 = db * 32 + hi * 8;
      f32x4 a = *(const f32x4*)(qr + d0);
      f32x4 c = *(const f32x4*)(qr + d0 + 4);
      bf16x8 f;
      f[0] = (short)f2bf(a[0] * SCALE_); f[1] = (short)f2bf(a[1] * SCALE_);
      f[2] = (short)f2bf(a[2] * SCALE_); f[3] = (short)f2bf(a[3] * SCALE_);
      f[4] = (short)f2bf(c[0] * SCALE_); f[5] = (short)f2bf(c[1] * SCALE_);
      f[6] = (short)f2bf(c[2] * SCALE_); f[7] = (short)f2bf(c[3] * SCALE_);
      qf[db] = f;
    }
  }

  f32x4 oacc[8];
#pragma unroll
  for (int i = 0; i < 8; ++i) oacc[i] = (f32x4){0.f, 0.f, 0.f, 0.f};
  float mrow[4], lrow[4];
#pragma unroll
  for (int i = 0; i < 4; ++i) { mrow[i] = -1e30f; lrow[i] = 0.f; }

  // ---- staging: thread -> (kv row c, d-chunk e); prefetch regs ----
  const int c = tid >> 3;            // kv column within tile (0..63)
  const int e = tid & 7;
  f32x4 kreg[4], vreg[4];

  auto issue_loads = [&](int t) {
    const int kgi = t * KT_ + c;     // global key index
    const float *kr, *vr;
    if (kgi < CTX_) {
      const int pb = btab[b * BPS_ + (kgi >> 8)];
      const size_t base = ((size_t)(pb * BLKSZ_ + (kgi & 255)) * HKV_ + hkv) * D_;
      kr = kcache + base; vr = vcache + base;
    } else {
      const size_t base = ((size_t)(b * LQ_ + (kgi - CTX_)) * HKV_ + hkv) * D_;
      kr = kcur + base;  vr = vcur + base;
    }
#pragma unroll
    for (int i2 = 0; i2 < 4; ++i2) {
      const int d0 = (e + i2 * 8) * 4;
      kreg[i2] = *(const f32x4*)(kr + d0);
      vreg[i2] = *(const f32x4*)(vr + d0);
    }
  };

  auto write_lds = [&]() {
#pragma unroll
    for (int i2 = 0; i2 < 4; ++i2) {
      const int d0 = (e + i2 * 8) * 4;
      f32x4 kv = kreg[i2];
      unsigned w0 = (unsigned)f2bf(kv[0]) | ((unsigned)f2bf(kv[1]) << 16);
      unsigned w1 = (unsigned)f2bf(kv[2]) | ((unsigned)f2bf(kv[3]) << 16);
      *(unsigned*)&Kl[c][d0]     = w0;
      *(unsigned*)&Kl[c][d0 + 2] = w1;
      f32x4 vv = vreg[i2];
      Vl[d0 + 0][c] = (short)f2bf(vv[0]);
      Vl[d0 + 1][c] = (short)f2bf(vv[1]);
      Vl[d0 + 2][c] = (short)f2bf(vv[2]);
      Vl[d0 + 3][c] = (short)f2bf(vv[3]);
    }
  };

  issue_loads(0);

  for (int t = 0; t < ntiles; ++t) {
    __syncthreads();   // prev compute done reading LDS; drains loads for t
    write_lds();
    __syncthreads();   // tile visible to all waves (no vmem in flight here)
    if (t + 1 < ntiles) issue_loads(t + 1);   // fly during compute(t)

    // ---- S = Q K^T  (16 q rows x 64 cols), 16 MFMAs ----
    f32x4 sacc[4];
#pragma unroll
    for (int cs = 0; cs < 4; ++cs) sacc[cs] = (f32x4){0.f, 0.f, 0.f, 0.f};
#pragma unroll
    for (int cs = 0; cs < 4; ++cs) {
#pragma unroll
      for (int db = 0; db < 4; ++db) {
        // b_frag: B[k=hi*8+j][col=lo] = K[cs*16+lo][db*32+hi*8+j]
        bf16x8 kf = *(const bf16x8*)&Kl[cs * 16 + lo][db * 32 + hi * 8];
        sacc[cs] = __builtin_amdgcn_mfma_f32_16x16x32_bf16(qf[db], kf, sacc[cs], 0, 0, 0);
      }
    }

    // ---- online softmax (row = hi*4+i, cols spread over lanes 0..15) ----
#pragma unroll
    for (int i = 0; i < 4; ++i) {
      float mx = fmaxf(fmaxf(sacc[0][i], sacc[1][i]), fmaxf(sacc[2][i], sacc[3][i]));
      mx = fmaxf(mx, __shfl_xor(mx, 1));
      mx = fmaxf(mx, __shfl_xor(mx, 2));
      mx = fmaxf(mx, __shfl_xor(mx, 4));
      mx = fmaxf(mx, __shfl_xor(mx, 8));
      const float mnew = fmaxf(mrow[i], mx);
      const float sc = __expf(mrow[i] - mnew);
      mrow[i] = mnew;
      float rs = 0.f;
#pragma unroll
      for (int cs = 0; cs < 4; ++cs) {
        const float p = __expf(sacc[cs][i] - mnew);
        sacc[cs][i] = p;
        rs += p;
      }
      rs += __shfl_xor(rs, 1);
      rs += __shfl_xor(rs, 2);
      rs += __shfl_xor(rs, 4);
      rs += __shfl_xor(rs, 8);
      lrow[i] = lrow[i] * sc + rs;
#pragma unroll
      for (int dt = 0; dt < 8; ++dt) oacc[dt][i] *= sc;
    }

    // ---- P -> LDS (wave-private; DS ops are in-order within a wave) ----
#pragma unroll
    for (int cs = 0; cs < 4; ++cs)
#pragma unroll
      for (int i = 0; i < 4; ++i)
        Pl[wave][hi * 4 + i][cs * 16 + lo] = (short)f2bf(sacc[cs][i]);

    // ---- O += P V  (16 MFMAs) ----
#pragma unroll
    for (int ch = 0; ch < 2; ++ch) {
      // a_frag: P[row=lo][k=ch*32+hi*8+j]
      bf16x8 pf = *(const bf16x8*)&Pl[wave][lo][ch * 32 + hi * 8];
#pragma unroll
      for (int dt = 0; dt < 8; ++dt) {
        // b_frag: V[k=ch*32+hi*8+j][col=dt*16+lo] = Vl[dt*16+lo][ch*32+hi*8+j]
        bf16x8 vf = *(const bf16x8*)&Vl[dt * 16 + lo][ch * 32 + hi * 8];
        oacc[dt] = __builtin_amdgcn_mfma_f32_16x16x32_bf16(pf, vf, oacc[dt], 0, 0, 0);
      }
    }
  }

  // ---- epilogue: out[b][q][hq][d] = oacc / l ----
#pragma unroll
  for (int i = 0; i < 4; ++i) {
    const int row = hi * 4 + i;
    const float inv = 1.f / lrow[i];
    float* orow = out + ((size_t)(b * LQ_ + qrow0 + row) * HQ_ + hq) * D_;
#pragma unroll
    for (int dt = 0; dt < 8; ++dt)
      orow[dt * 16 + lo] = oacc[dt][i] * inv;
  }
}

extern "C" void kernel_launch(void* const* d_in, const int* in_sizes, int n_in,
                              void* d_out, int out_size, void* d_ws, size_t ws_size,
                              hipStream_t stream) {
  (void)in_sizes; (void)n_in; (void)out_size; (void)d_ws; (void)ws_size;
  const float* q      = (const float*)d_in[0];
  const float* k      = (const float*)d_in[1];
  const float* v      = (const float*)d_in[2];
  const float* kcache = (const float*)d_in[3];
  const float* vcache = (const float*)d_in[4];
  const int*   btab   = (const int*)d_in[5];
  // d_in[6] (allow_mask) is implied by the loop bound — not read.
  float* out = (float*)d_out;

  block_attn_kernel<<<dim3(B_ * HKV_ * (LQ_ / 64)), dim3(512), 0, stream>>>(
      q, k, v, kcache, vcache, btab, out);
}

// Round 3
// 120.713 us; speedup vs baseline: 1.7711x; 1.0781x over previous
//
#include <hip/hip_runtime.h>
#include <hip/hip_bf16.h>

// BlockAttention: paged KV-cache prefill attention, block-causal mask.
// B=4, LQ=512, HQ=16, HKV=8, D=128, CTX=2048, LK=2560.
// R1: XCD-aware block index + register prefetch.
// R2: XOR-swizzled conflict-free K/V LDS layouts; V staged as u32 row-pairs
//     (no scalar u16 transpose writes); double-buffered K/V with ONE
//     barrier per tile (write next tile after compute, before barrier).

#define B_    4
#define LQ_   512
#define HQ_   16
#define HKV_  8
#define D_    128
#define BLKSZ_ 256
#define BPS_  8
#define CTX_  2048
#define DIFFB_ 128
#define KT_   64
#define SCALE_ 0.08838834764831845f

typedef __attribute__((ext_vector_type(4))) float f32x4;
typedef __attribute__((ext_vector_type(8))) short bf16x8;

__device__ __forceinline__ unsigned short f2bf(float f) {
  union { float f; unsigned u; } x; x.f = f;
  unsigned r = x.u + 0x7FFFu + ((x.u >> 16) & 1u);   // RNE
  return (unsigned short)(r >> 16);
}
__device__ __forceinline__ unsigned packbf(float a, float b) {
  return (unsigned)f2bf(a) | ((unsigned)f2bf(b) << 16);
}

// ---- XOR-swizzled LDS index maps (units: shorts) ----
// K tile: logical (kv in [0,64), d in [0,128)). 16B chunk = 8 shorts.
// chunk' = (d>>3) ^ (kv&15)  -> kf reads even over banks, u32 writes free.
__device__ __forceinline__ int kidx(int kv, int d) {
  return kv * 128 + ((((d >> 3) ^ kv) & 15) << 3) + (d & 7);
}
// V tile (transposed): logical (d in [0,128), kv in [0,64)).
// chunk' = (kv>>3) ^ (d&7) ^ ((d>>3)&7) -> vf reads even, pair-writes free.
__device__ __forceinline__ int vidx(int d, int kv) {
  return d * 64 + ((((kv >> 3) ^ d ^ (d >> 3)) & 7) << 3) + (kv & 7);
}

__global__ __launch_bounds__(512)
void block_attn_kernel(const float* __restrict__ qg,
                       const float* __restrict__ kcur,
                       const float* __restrict__ vcur,
                       const float* __restrict__ kcache,
                       const float* __restrict__ vcache,
                       const int*   __restrict__ btab,
                       float*       __restrict__ out) {
  // grid 256: blk = qb*32 + b*8 + hkv (qb high bits -> same (b,hkv) per XCD)
  const int blk  = blockIdx.x;
  const int hkv  = blk & 7;
  const int b    = (blk >> 3) & 3;
  const int qb   = blk >> 5;
  const int tid  = threadIdx.x;
  const int wave = tid >> 6;
  const int lane = tid & 63;
  const int lo   = lane & 15;
  const int hi   = lane >> 4;
  const int hq   = hkv * 2 + (wave >> 2);
  const int qrow0 = qb * 64 + (wave & 3) * 16;
  const int limit  = CTX_ + (qb / 2 + 1) * DIFFB_;
  const int ntiles = limit / KT_;

  __shared__ short Kl[2][KT_ * D_];     // 2 x 16 KiB, swizzled
  __shared__ short Vl[2][D_ * KT_];     // 2 x 16 KiB, swizzled (transposed V)
  __shared__ short Pl[8][16][72];       // per-wave P round-trip (pad 72)

  // ---- Q fragments (scaled, bf16). a_frag: A[row=lo][k=hi*8+j] ----
  bf16x8 qf[4];
  {
    const float* qr = qg + ((size_t)((b * LQ_ + qrow0 + lo)) * HQ_ + hq) * D_;
#pragma unroll
    for (int db = 0; db < 4; ++db) {
      const int d0 = db * 32 + hi * 8;
      f32x4 a = *(const f32x4*)(qr + d0);
      f32x4 c4 = *(const f32x4*)(qr + d0 + 4);
      bf16x8 f;
      f[0] = (short)f2bf(a[0] * SCALE_); f[1] = (short)f2bf(a[1] * SCALE_);
      f[2] = (short)f2bf(a[2] * SCALE_); f[3] = (short)f2bf(a[3] * SCALE_);
      f[4] = (short)f2bf(c4[0] * SCALE_); f[5] = (short)f2bf(c4[1] * SCALE_);
      f[6] = (short)f2bf(c4[2] * SCALE_); f[7] = (short)f2bf(c4[3] * SCALE_);
      qf[db] = f;
    }
  }

  f32x4 oacc[8];
#pragma unroll
  for (int i = 0; i < 8; ++i) oacc[i] = (f32x4){0.f, 0.f, 0.f, 0.f};
  float mrow[4], lrow[4];
#pragma unroll
  for (int i = 0; i < 4; ++i) { mrow[i] = -1e30f; lrow[i] = 0.f; }

  // ---- staging thread mapping ----
  const int c  = tid >> 3;              // K row (0..63); V pair = c&~1
  const int e  = tid & 7;               // K d-chunk selector
  const int ep = ((c & 1) << 3) | e;    // V d-chunk selector (0..15)
  const int r0 = c & ~1;                // V row pair base
  f32x4 kreg[4], vreg[4];

  auto issue_loads = [&](int t) {
    const int kbase = t * KT_;          // tile never straddles CTX (2048%64==0)
    const float *kr, *vr0;
    if (kbase < CTX_) {
      const int pb = btab[b * BPS_ + (kbase >> 8)];
      const int ro = (kbase & 255);
      kr  = kcache + ((size_t)(pb * BLKSZ_ + ro + c)  * HKV_ + hkv) * D_;
      vr0 = vcache + ((size_t)(pb * BLKSZ_ + ro + r0) * HKV_ + hkv) * D_;
    } else {
      const int cur = kbase - CTX_;
      kr  = kcur + ((size_t)(b * LQ_ + cur + c)  * HKV_ + hkv) * D_;
      vr0 = vcur + ((size_t)(b * LQ_ + cur + r0) * HKV_ + hkv) * D_;
    }
#pragma unroll
    for (int i2 = 0; i2 < 4; ++i2)
      kreg[i2] = *(const f32x4*)(kr + (e + i2 * 8) * 4);
    const int vd0 = ep * 8;
    vreg[0] = *(const f32x4*)(vr0 + vd0);
    vreg[1] = *(const f32x4*)(vr0 + vd0 + 4);
    vreg[2] = *(const f32x4*)(vr0 + HKV_ * D_ + vd0);
    vreg[3] = *(const f32x4*)(vr0 + HKV_ * D_ + vd0 + 4);
  };

  auto write_lds = [&](int bsel) {
    short* Kb = Kl[bsel];
    short* Vb = Vl[bsel];
#pragma unroll
    for (int i2 = 0; i2 < 4; ++i2) {
      const int d0 = (e + i2 * 8) * 4;
      f32x4 kv = kreg[i2];
      *(unsigned*)&Kb[kidx(c, d0)]     = packbf(kv[0], kv[1]);
      *(unsigned*)&Kb[kidx(c, d0 + 2)] = packbf(kv[2], kv[3]);
    }
    const int vd0 = ep * 8;
#pragma unroll
    for (int j = 0; j < 4; ++j) {
      *(unsigned*)&Vb[vidx(vd0 + j,     r0)] = packbf(vreg[0][j], vreg[2][j]);
      *(unsigned*)&Vb[vidx(vd0 + 4 + j, r0)] = packbf(vreg[1][j], vreg[3][j]);
    }
  };

  issue_loads(0);
  write_lds(0);
  __syncthreads();

  for (int t = 0; t < ntiles; ++t) {
    const int bsel = t & 1;
    const short* Kb = Kl[bsel];
    const short* Vb = Vl[bsel];
    if (t + 1 < ntiles) issue_loads(t + 1);   // fly under compute(t)

    // ---- S = Q K^T  (16 q rows x 64 cols), 16 MFMAs ----
    f32x4 sacc[4];
#pragma unroll
    for (int cs = 0; cs < 4; ++cs) sacc[cs] = (f32x4){0.f, 0.f, 0.f, 0.f};
#pragma unroll
    for (int cs = 0; cs < 4; ++cs) {
#pragma unroll
      for (int db = 0; db < 4; ++db) {
        bf16x8 kf = *(const bf16x8*)&Kb[kidx(cs * 16 + lo, db * 32 + hi * 8)];
        sacc[cs] = __builtin_amdgcn_mfma_f32_16x16x32_bf16(qf[db], kf, sacc[cs], 0, 0, 0);
      }
    }

    // ---- online softmax (row = hi*4+i, cols spread over lanes 0..15) ----
#pragma unroll
    for (int i = 0; i < 4; ++i) {
      float mx = fmaxf(fmaxf(sacc[0][i], sacc[1][i]), fmaxf(sacc[2][i], sacc[3][i]));
      mx = fmaxf(mx, __shfl_xor(mx, 1));
      mx = fmaxf(mx, __shfl_xor(mx, 2));
      mx = fmaxf(mx, __shfl_xor(mx, 4));
      mx = fmaxf(mx, __shfl_xor(mx, 8));
      const float mnew = fmaxf(mrow[i], mx);
      const float sc = __expf(mrow[i] - mnew);
      mrow[i] = mnew;
      float rs = 0.f;
#pragma unroll
      for (int cs = 0; cs < 4; ++cs) {
        const float p = __expf(sacc[cs][i] - mnew);
        sacc[cs][i] = p;
        rs += p;
      }
      rs += __shfl_xor(rs, 1);
      rs += __shfl_xor(rs, 2);
      rs += __shfl_xor(rs, 4);
      rs += __shfl_xor(rs, 8);
      lrow[i] = lrow[i] * sc + rs;
#pragma unroll
      for (int dt = 0; dt < 8; ++dt) oacc[dt][i] *= sc;
    }

    // ---- P -> LDS (wave-private) ----
#pragma unroll
    for (int cs = 0; cs < 4; ++cs)
#pragma unroll
      for (int i = 0; i < 4; ++i)
        Pl[wave][hi * 4 + i][cs * 16 + lo] = (short)f2bf(sacc[cs][i]);

    // ---- O += P V  (16 MFMAs) ----
#pragma unroll
    for (int ch = 0; ch < 2; ++ch) {
      bf16x8 pf = *(const bf16x8*)&Pl[wave][lo][ch * 32 + hi * 8];
#pragma unroll
      for (int dt = 0; dt < 8; ++dt) {
        bf16x8 vf = *(const bf16x8*)&Vb[vidx(dt * 16 + lo, ch * 32 + hi * 8)];
        oacc[dt] = __builtin_amdgcn_mfma_f32_16x16x32_bf16(pf, vf, oacc[dt], 0, 0, 0);
      }
    }

    if (t + 1 < ntiles) write_lds(bsel ^ 1);  // overlap with others' compute
    __syncthreads();
  }

  // ---- epilogue: out[b][q][hq][d] = oacc / l ----
#pragma unroll
  for (int i = 0; i < 4; ++i) {
    const int row = hi * 4 + i;
    const float inv = 1.f / lrow[i];
    float* orow = out + ((size_t)(b * LQ_ + qrow0 + row) * HQ_ + hq) * D_;
#pragma unroll
    for (int dt = 0; dt < 8; ++dt)
      orow[dt * 16 + lo] = oacc[dt][i] * inv;
  }
}

extern "C" void kernel_launch(void* const* d_in, const int* in_sizes, int n_in,
                              void* d_out, int out_size, void* d_ws, size_t ws_size,
                              hipStream_t stream) {
  (void)in_sizes; (void)n_in; (void)out_size; (void)d_ws; (void)ws_size;
  const float* q      = (const float*)d_in[0];
  const float* k      = (const float*)d_in[1];
  const float* v      = (const float*)d_in[2];
  const float* kcache = (const float*)d_in[3];
  const float* vcache = (const float*)d_in[4];
  const int*   btab   = (const int*)d_in[5];
  float* out = (float*)d_out;

  block_attn_kernel<<<dim3(B_ * HKV_ * (LQ_ / 64)), dim3(512), 0, stream>>>(
      q, k, v, kcache, vcache, btab, out);
}

// Round 4
// 93.248 us; speedup vs baseline: 2.2928x; 1.2945x over previous
//
#include <hip/hip_runtime.h>
#include <hip/hip_bf16.h>

// BlockAttention: paged KV-cache prefill attention, block-causal mask.
// B=4, LQ=512, HQ=16, HKV=8, D=128, CTX=2048, LK=2560.
// R1: XCD-aware block index + register prefetch.
// R2: swizzled K/V LDS, double-buffer, one barrier/tile.
// R3: swapped QK^T (S^T) -> in-register softmax (lane owns one q-row);
//     PV with per-lane k-relabel: pa packed in-lane (zero shuffles), V^T
//     stored with kv bits[5:4]<->[3:2] permuted so the A-frag is one b128;
//     P LDS tile eliminated; cvt_pk bf16 conversions; defer-max (THR=8).

#define B_    4
#define LQ_   512
#define HQ_   16
#define HKV_  8
#define D_    128
#define BLKSZ_ 256
#define BPS_  8
#define CTX_  2048
#define DIFFB_ 128
#define KT_   64
#define SCALE_ 0.08838834764831845f

typedef __attribute__((ext_vector_type(4))) float f32x4;
typedef __attribute__((ext_vector_type(8))) short bf16x8;

__device__ __forceinline__ unsigned cvt_pk2(float a, float b) {
  union { __hip_bfloat162 h; unsigned u; } x;
  x.h = __float22bfloat162_rn(float2{a, b});
  return x.u;
}
union bf8u { bf16x8 v; unsigned u[4]; };

// ---- K tile swizzle (units: shorts), 16B-chunk XOR ----
__device__ __forceinline__ int kidx(int kv, int d) {
  return kv * 128 + ((((d >> 3) ^ kv) & 15) << 3) + (d & 7);
}
// ---- V^T tile swizzle; p is the PHYSICAL (permuted) kv index ----
__device__ __forceinline__ int vidx(int d, int p) {
  return d * 64 + ((((p >> 3) ^ d ^ (d >> 3)) & 7) << 3) + (p & 7);
}
// kv bit-permute: swap bits[5:4] <-> bits[3:2] (involution)
__device__ __forceinline__ int pkmap(int kv) {
  return ((kv & 12) << 2) | ((kv & 48) >> 2) | (kv & 3);
}

__global__ __launch_bounds__(512)
void block_attn_kernel(const float* __restrict__ qg,
                       const float* __restrict__ kcur,
                       const float* __restrict__ vcur,
                       const float* __restrict__ kcache,
                       const float* __restrict__ vcache,
                       const int*   __restrict__ btab,
                       float*       __restrict__ out) {
  // grid 256: blk = qb*32 + b*8 + hkv (qb high bits -> same (b,hkv) per XCD)
  const int blk  = blockIdx.x;
  const int hkv  = blk & 7;
  const int b    = (blk >> 3) & 3;
  const int qb   = blk >> 5;
  const int tid  = threadIdx.x;
  const int lane = tid & 63;
  const int wave = tid >> 6;
  const int lo   = lane & 15;
  const int hi   = lane >> 4;
  const int hq   = hkv * 2 + (wave >> 2);
  const int qrow0 = qb * 64 + (wave & 3) * 16;
  const int limit  = CTX_ + (qb / 2 + 1) * DIFFB_;
  const int ntiles = limit / KT_;

  __shared__ __align__(16) short Kl[2][KT_ * D_];   // 2 x 16 KiB, swizzled
  __shared__ __align__(16) short Vl[2][D_ * KT_];   // 2 x 16 KiB, V^T permuted+swizzled

  // ---- Q fragments (scaled bf16). frag: [row/col=lo][k=hi*8+j] ----
  bf16x8 qf[4];
  {
    const float* qr = qg + ((size_t)((b * LQ_ + qrow0 + lo)) * HQ_ + hq) * D_;
#pragma unroll
    for (int db = 0; db < 4; ++db) {
      const int d0 = db * 32 + hi * 8;
      f32x4 a = *(const f32x4*)(qr + d0);
      f32x4 c4 = *(const f32x4*)(qr + d0 + 4);
      bf8u f;
      f.u[0] = cvt_pk2(a[0] * SCALE_, a[1] * SCALE_);
      f.u[1] = cvt_pk2(a[2] * SCALE_, a[3] * SCALE_);
      f.u[2] = cvt_pk2(c4[0] * SCALE_, c4[1] * SCALE_);
      f.u[3] = cvt_pk2(c4[2] * SCALE_, c4[3] * SCALE_);
      qf[db] = f.v;
    }
  }

  f32x4 oacc[8];
#pragma unroll
  for (int i = 0; i < 8; ++i) oacc[i] = (f32x4){0.f, 0.f, 0.f, 0.f};
  float mrow = -1e30f, lrow = 0.f;     // per-lane: ONE q-row (q = lo)

  // ---- staging thread mapping ----
  const int c  = tid >> 3;              // K row (0..63); V pair = c&~1
  const int e  = tid & 7;               // K d-chunk selector
  const int ep = ((c & 1) << 3) | e;    // V d-chunk selector (0..15)
  const int r0 = c & ~1;                // V row-pair base (even)
  const int pr = pkmap(r0);             // physical (permuted) position, even
  f32x4 kreg[4], vreg[4];

  auto issue_loads = [&](int t) {
    const int kbase = t * KT_;          // tile never straddles CTX (2048%64==0)
    const float *kr, *vr0;
    if (kbase < CTX_) {
      const int pb = btab[b * BPS_ + (kbase >> 8)];
      const int ro = (kbase & 255);
      kr  = kcache + ((size_t)(pb * BLKSZ_ + ro + c)  * HKV_ + hkv) * D_;
      vr0 = vcache + ((size_t)(pb * BLKSZ_ + ro + r0) * HKV_ + hkv) * D_;
    } else {
      const int cur = kbase - CTX_;
      kr  = kcur + ((size_t)(b * LQ_ + cur + c)  * HKV_ + hkv) * D_;
      vr0 = vcur + ((size_t)(b * LQ_ + cur + r0) * HKV_ + hkv) * D_;
    }
#pragma unroll
    for (int i2 = 0; i2 < 4; ++i2)
      kreg[i2] = *(const f32x4*)(kr + (e + i2 * 8) * 4);
    const int vd0 = ep * 8;
    vreg[0] = *(const f32x4*)(vr0 + vd0);
    vreg[1] = *(const f32x4*)(vr0 + vd0 + 4);
    vreg[2] = *(const f32x4*)(vr0 + HKV_ * D_ + vd0);
    vreg[3] = *(const f32x4*)(vr0 + HKV_ * D_ + vd0 + 4);
  };

  auto write_lds = [&](int bsel) {
    short* Kb = Kl[bsel];
    short* Vb = Vl[bsel];
#pragma unroll
    for (int i2 = 0; i2 < 4; ++i2) {
      const int d0 = (e + i2 * 8) * 4;
      f32x4 kv = kreg[i2];
      *(unsigned*)&Kb[kidx(c, d0)]     = cvt_pk2(kv[0], kv[1]);
      *(unsigned*)&Kb[kidx(c, d0 + 2)] = cvt_pk2(kv[2], kv[3]);
    }
    const int vd0 = ep * 8;
#pragma unroll
    for (int j = 0; j < 4; ++j) {
      // u32 = {V[r0][d], V[r0+1][d]} stored at physical kv = pr (pkmap'd)
      *(unsigned*)&Vb[vidx(vd0 + j,     pr)] = cvt_pk2(vreg[0][j], vreg[2][j]);
      *(unsigned*)&Vb[vidx(vd0 + 4 + j, pr)] = cvt_pk2(vreg[1][j], vreg[3][j]);
    }
  };

  issue_loads(0);
  write_lds(0);
  __syncthreads();

  for (int t = 0; t < ntiles; ++t) {
    const int bsel = t & 1;
    const short* Kb = Kl[bsel];
    const short* Vb = Vl[bsel];
    if (t + 1 < ntiles) issue_loads(t + 1);   // fly under compute(t)

    // ---- S^T = K Q^T : sacc[cs][i] = S[q=lo][k=cs*16+hi*4+i] ----
    f32x4 sacc[4];
#pragma unroll
    for (int cs = 0; cs < 4; ++cs) sacc[cs] = (f32x4){0.f, 0.f, 0.f, 0.f};
#pragma unroll
    for (int cs = 0; cs < 4; ++cs) {
#pragma unroll
      for (int db = 0; db < 4; ++db) {
        bf16x8 kf = *(const bf16x8*)&Kb[kidx(cs * 16 + lo, db * 32 + hi * 8)];
        // swapped operands: A = K-frag, B = Q-frag  ->  D = S^T
        sacc[cs] = __builtin_amdgcn_mfma_f32_16x16x32_bf16(kf, qf[db], sacc[cs], 0, 0, 0);
      }
    }

    // ---- in-register online softmax (one q-row per lane) ----
    float mx;
    {
      float m0 = fmaxf(fmaxf(sacc[0][0], sacc[0][1]), fmaxf(sacc[0][2], sacc[0][3]));
      float m1 = fmaxf(fmaxf(sacc[1][0], sacc[1][1]), fmaxf(sacc[1][2], sacc[1][3]));
      float m2 = fmaxf(fmaxf(sacc[2][0], sacc[2][1]), fmaxf(sacc[2][2], sacc[2][3]));
      float m3 = fmaxf(fmaxf(sacc[3][0], sacc[3][1]), fmaxf(sacc[3][2], sacc[3][3]));
      mx = fmaxf(fmaxf(m0, m1), fmaxf(m2, m3));
      mx = fmaxf(mx, __shfl_xor(mx, 16));
      mx = fmaxf(mx, __shfl_xor(mx, 32));
    }
    const bool keep = __all(mx - mrow <= 8.0f);   // defer-max (T13)
    const float mnew = keep ? mrow : fmaxf(mrow, mx);
    float rs = 0.f;
#pragma unroll
    for (int cs = 0; cs < 4; ++cs)
#pragma unroll
      for (int i = 0; i < 4; ++i) {
        const float p = __expf(sacc[cs][i] - mnew);
        sacc[cs][i] = p;
        rs += p;
      }
    rs += __shfl_xor(rs, 16);
    rs += __shfl_xor(rs, 32);
    if (keep) {
      lrow += rs;
    } else {
      const float sc = __expf(mrow - mnew);
      lrow = lrow * sc + rs;
      mrow = mnew;
#pragma unroll
      for (int dt = 0; dt < 8; ++dt) oacc[dt] *= sc;
    }

    // ---- pack P in-lane: pa[ch] covers k_eff = (2ch+(j>>2))*16+hi*4+(j&3) ----
    bf16x8 pa[2];
#pragma unroll
    for (int ch = 0; ch < 2; ++ch) {
      bf8u p;
      p.u[0] = cvt_pk2(sacc[2 * ch][0],     sacc[2 * ch][1]);
      p.u[1] = cvt_pk2(sacc[2 * ch][2],     sacc[2 * ch][3]);
      p.u[2] = cvt_pk2(sacc[2 * ch + 1][0], sacc[2 * ch + 1][1]);
      p.u[3] = cvt_pk2(sacc[2 * ch + 1][2], sacc[2 * ch + 1][3]);
      pa[ch] = p.v;
    }

    // ---- O^T += V^T P^T : A = V^T-frag (b128, permuted layout), B = pa ----
#pragma unroll
    for (int ch = 0; ch < 2; ++ch) {
#pragma unroll
      for (int dt = 0; dt < 8; ++dt) {
        bf16x8 vf = *(const bf16x8*)&Vb[vidx(dt * 16 + lo, hi * 16 + ch * 8)];
        oacc[dt] = __builtin_amdgcn_mfma_f32_16x16x32_bf16(vf, pa[ch], oacc[dt], 0, 0, 0);
      }
    }

    if (t + 1 < ntiles) write_lds(bsel ^ 1);  // overlap with others' compute
    __syncthreads();
  }

  // ---- epilogue: lane owns O[q=lo][dout = dt*16 + hi*4 + i] ----
  const float inv = 1.f / lrow;
  float* orow = out + ((size_t)(b * LQ_ + qrow0 + lo) * HQ_ + hq) * D_;
#pragma unroll
  for (int dt = 0; dt < 8; ++dt) {
    f32x4 o4 = oacc[dt] * inv;
    *(f32x4*)(orow + dt * 16 + hi * 4) = o4;
  }
}

extern "C" void kernel_launch(void* const* d_in, const int* in_sizes, int n_in,
                              void* d_out, int out_size, void* d_ws, size_t ws_size,
                              hipStream_t stream) {
  (void)in_sizes; (void)n_in; (void)out_size; (void)d_ws; (void)ws_size;
  const float* q      = (const float*)d_in[0];
  const float* k      = (const float*)d_in[1];
  const float* v      = (const float*)d_in[2];
  const float* kcache = (const float*)d_in[3];
  const float* vcache = (const float*)d_in[4];
  const int*   btab   = (const int*)d_in[5];
  float* out = (float*)d_out;

  block_attn_kernel<<<dim3(B_ * HKV_ * (LQ_ / 64)), dim3(512), 0, stream>>>(
      q, k, v, kcache, vcache, btab, out);
}